// Round 3
// baseline (237.034 us; speedup 1.0000x reference)
//
#include <hip/hip_runtime.h>

#define N_PTS 100000
#define KNB   12
#define TLEN  365
#define ROWS_PER_BLOCK 64
#define PARAMS_BYTES ((size_t)N_PTS * 12 * sizeof(float))

__device__ __forceinline__ float bf2f(unsigned short u) {
    return __uint_as_float(((unsigned int)u) << 16);
}
__device__ __forceinline__ unsigned short f2bf(float f) {
    unsigned int x = __float_as_uint(f);
    unsigned int r = (x + 0x7FFFu + ((x >> 16) & 1u)) >> 16;
    return (unsigned short)r;
}

// Runtime input-dtype detection: time_vector[0] == 0.0 exactly.
// f32 layout  -> first 4 bytes are 0x00000000.
// bf16 layout -> first 4 bytes are {0x0000, bf16(1/365.25)=0x3B33} != 0.
__device__ __forceinline__ bool detect_bf16(const void* tvec) {
    return ((const unsigned int*)tvec)[0] != 0u;
}

// Scalar dual-dtype load.
__device__ __forceinline__ float ld(const void* p, size_t i, bool b16) {
    if (b16) return bf2f(((const unsigned short*)p)[i]);
    return ((const float*)p)[i];
}

// Param row for pixel n: [c, trend, a0..a3, b0..b3]
// a_i = amp_s*cos(ph_s), b_i = amp_s*sin(ph_s);
// cos/sin(atan2(mim,mre)) computed as mre/h, mim/h (no atan2).
__device__ void compute_params(
    int n, bool b16,
    const void* __restrict__ amps,
    const void* __restrict__ phs,
    const void* __restrict__ wgts,
    const int*  __restrict__ idx,
    const void* __restrict__ coff,
    const void* __restrict__ trend,
    float outp[12])
{
    float sx[4]  = {0,0,0,0}, sxx[4] = {0,0,0,0}, swx[4] = {0,0,0,0};
    float wre[4] = {0,0,0,0}, wim[4] = {0,0,0,0};

    #pragma unroll
    for (int k = 0; k < KNB; ++k) {
        int j = idx[(size_t)n * KNB + k];
        j = (j < 0) ? 0 : ((j >= N_PTS) ? N_PTS - 1 : j);  // defensive clamp
        float wk = ld(wgts, (size_t)n * KNB + k, b16);
        #pragma unroll
        for (int i = 0; i < 4; ++i) {
            float a = ld(amps, (size_t)j * 4 + i, b16);
            float p = ld(phs,  (size_t)j * 4 + i, b16);
            sx[i]  += a;
            sxx[i] += a * a;
            swx[i] += wk * a;
            float s, c;
            __sincosf(p, &s, &c);
            wre[i] += wk * c;
            wim[i] += wk * s;
        }
    }

    outp[0] = ld(coff,  n, b16);
    outp[1] = ld(trend, n, b16);
    #pragma unroll
    for (int i = 0; i < 4; ++i) {
        float aof = ld(amps, (size_t)n * 4 + i, b16);
        float pof = ld(phs,  (size_t)n * 4 + i, b16);

        float mean  = sx[i] * (1.0f / KNB);
        float var   = fmaxf((sxx[i] - (float)KNB * mean * mean) * (1.0f / (KNB - 1)), 0.0f);
        float afa   = 0.25f / (1.0f + 0.1f * var);
        float amp_s = (1.0f - afa) * aof + afa * swx[i];

        float cons = sqrtf(wre[i] * wre[i] + wim[i] * wim[i]);
        float afp  = 0.15f * cons;
        float s, c;
        __sincosf(pof, &s, &c);
        float mre = (1.0f - afp) * c + afp * wre[i];
        float mim = (1.0f - afp) * s + afp * wim[i];
        float h   = sqrtf(mre * mre + mim * mim);
        float ai, bi;
        if (h > 1e-30f) {
            float scale = amp_s / h;
            ai = mre * scale;
            bi = mim * scale;
        } else {  // atan2(0,0)=0 -> cos=1, sin=0
            ai = amp_s;
            bi = 0.0f;
        }
        outp[2 + i] = ai;
        outp[6 + i] = bi;
    }
}

__device__ __forceinline__ void synth_row_store(
    void* out, size_t o, float v, bool b16)
{
    if (b16) ((unsigned short*)out)[o] = f2bf(v);
    else     ((float*)out)[o] = v;
}

// ---------------- Path A: two kernels via d_ws ------------------------------

__global__ __launch_bounds__(256) void smooth_kernel(
    const void* __restrict__ amps,
    const void* __restrict__ phs,
    const void* __restrict__ wgts,
    const int*  __restrict__ idx,
    const void* __restrict__ coff,
    const void* __restrict__ trend,
    const void* __restrict__ tvec,
    float*      __restrict__ params)
{
    int n = blockIdx.x * blockDim.x + threadIdx.x;
    if (n >= N_PTS) return;
    bool b16 = detect_bf16(tvec);
    float outp[12];
    compute_params(n, b16, amps, phs, wgts, idx, coff, trend, outp);
    #pragma unroll
    for (int i = 0; i < 12; ++i) params[(size_t)n * 12 + i] = outp[i];
}

__global__ __launch_bounds__(384) void synth_kernel(
    const float* __restrict__ params,
    const void*  __restrict__ tvec,
    void*        __restrict__ out)
{
    bool b16 = detect_bf16(tvec);
    int t = threadIdx.x;
    if (t >= TLEN) return;
    float tval = ld(tvec, t, b16);

    const float W0 = 25.132741228718345f;   // 2*pi*4
    const float W1 = 12.566370614359172f;   // 2*pi*2
    const float W2 = 6.283185307179586f;    // 2*pi*1
    const float W3 = 3.141592653589793f;    // 2*pi*0.5
    float s0, c0, s1, c1, s2, c2, s3, c3;
    __sincosf(W0 * tval, &s0, &c0);
    __sincosf(W1 * tval, &s1, &c1);
    __sincosf(W2 * tval, &s2, &c2);
    __sincosf(W3 * tval, &s3, &c3);

    int row0 = blockIdx.x * ROWS_PER_BLOCK;
    int rend = min(row0 + ROWS_PER_BLOCK, N_PTS);
    for (int n = row0; n < rend; ++n) {
        const float* p = params + (size_t)n * 12;  // uniform address -> s_load
        float v = fmaf(p[1], tval, p[0]);
        v = fmaf(p[2], s0, v);
        v = fmaf(p[3], s1, v);
        v = fmaf(p[4], s2, v);
        v = fmaf(p[5], s3, v);
        v = fmaf(p[6], c0, v);
        v = fmaf(p[7], c1, v);
        v = fmaf(p[8], c2, v);
        v = fmaf(p[9], c3, v);
        synth_row_store(out, (size_t)n * TLEN + t, v, b16);
    }
}

// ---------------- Path B: fused, zero-workspace -----------------------------

__global__ __launch_bounds__(384) void fused_kernel(
    const void* __restrict__ amps,
    const void* __restrict__ phs,
    const void* __restrict__ wgts,
    const int*  __restrict__ idx,
    const void* __restrict__ coff,
    const void* __restrict__ trend,
    const void* __restrict__ tvec,
    void*       __restrict__ out)
{
    __shared__ float P[ROWS_PER_BLOCK][12];   // 3 KB, scalar access only
    bool b16 = detect_bf16(tvec);

    int row0 = blockIdx.x * ROWS_PER_BLOCK;
    int tid  = threadIdx.x;

    if (tid < ROWS_PER_BLOCK) {
        int n = row0 + tid;
        if (n < N_PTS) {
            float outp[12];
            compute_params(n, b16, amps, phs, wgts, idx, coff, trend, outp);
            #pragma unroll
            for (int i = 0; i < 12; ++i) P[tid][i] = outp[i];
        }
    }
    __syncthreads();

    int t = tid;
    if (t >= TLEN) return;
    float tval = ld(tvec, t, b16);

    const float W0 = 25.132741228718345f;
    const float W1 = 12.566370614359172f;
    const float W2 = 6.283185307179586f;
    const float W3 = 3.141592653589793f;
    float s0, c0, s1, c1, s2, c2, s3, c3;
    __sincosf(W0 * tval, &s0, &c0);
    __sincosf(W1 * tval, &s1, &c1);
    __sincosf(W2 * tval, &s2, &c2);
    __sincosf(W3 * tval, &s3, &c3);

    int rend = min(row0 + ROWS_PER_BLOCK, N_PTS);
    for (int n = row0; n < rend; ++n) {
        int r = n - row0;
        float v = fmaf(P[r][1], tval, P[r][0]);
        v = fmaf(P[r][2], s0, v);
        v = fmaf(P[r][3], s1, v);
        v = fmaf(P[r][4], s2, v);
        v = fmaf(P[r][5], s3, v);
        v = fmaf(P[r][6], c0, v);
        v = fmaf(P[r][7], c1, v);
        v = fmaf(P[r][8], c2, v);
        v = fmaf(P[r][9], c3, v);
        synth_row_store(out, (size_t)n * TLEN + t, v, b16);
    }
}

extern "C" void kernel_launch(void* const* d_in, const int* in_sizes, int n_in,
                              void* d_out, int out_size, void* d_ws, size_t ws_size,
                              hipStream_t stream) {
    const void* tvec  = d_in[0];             // time_vector (365)
    const void* coff  = d_in[1];             // constant_offset (N)
    const void* trend = d_in[2];             // linear_trend (N)
    const void* amps  = d_in[3];             // seasonal_amplitudes (N,4)
    const void* phs   = d_in[4];             // seasonal_phases (N,4)
    const void* wgts  = d_in[5];             // neighbor_weights (N,12)
    const int*  idx   = (const int*)d_in[6]; // neighbor_indices (N,12) int32

    int nblk = (N_PTS + ROWS_PER_BLOCK - 1) / ROWS_PER_BLOCK;

    if (d_ws != nullptr && ws_size >= PARAMS_BYTES) {
        float* params = (float*)d_ws;  // N x 12 f32 = 4.8 MB
        smooth_kernel<<<(N_PTS + 255) / 256, 256, 0, stream>>>(
            amps, phs, wgts, idx, coff, trend, tvec, params);
        synth_kernel<<<nblk, 384, 0, stream>>>(params, tvec, d_out);
    } else {
        fused_kernel<<<nblk, 384, 0, stream>>>(
            amps, phs, wgts, idx, coff, trend, tvec, d_out);
    }
}

// Round 7
// 226.569 us; speedup vs baseline: 1.0462x; 1.0462x over previous
//
#include <hip/hip_runtime.h>

#define N_PTS 100000
#define KNB   12
#define TLEN  365
#define FUSED_ROWS 64
#define SYNTH_ROWS 16   // r7: only change vs round-3 PASS — synth grid 1563->6250 blocks
#define PARAMS_BYTES ((size_t)N_PTS * 12 * sizeof(float))

// ENVIRONMENT FACTS (rounds 0-6):
//  - Inputs are bf16 (r3 runtime probe chose bf16 path, passed, absmax 0.0625
//    = bf16 quantization floor). idx int32.
//  - Round-3 kernel code is the ONLY proven-correct variant. Rounds 4-6
//    changed (a) smooth to 4-thread/pixel + (b) hard-coded bf16 -> NaN.
//    Merge/alignment theories falsified (r6 volatile still NaN'd; r3's own
//    mergeable idx loads passed). Mechanism unknown => treat round-3 load
//    code as load-bearing; change only launch geometry / non-load code.

__device__ __forceinline__ float bf2f(unsigned short u) {
    return __uint_as_float(((unsigned int)u) << 16);
}
__device__ __forceinline__ unsigned short f2bf(float f) {
    unsigned int x = __float_as_uint(f);
    unsigned int r = (x + 0x7FFFu + ((x >> 16) & 1u)) >> 16;
    return (unsigned short)r;
}

// Runtime input-dtype detection: time_vector[0] == 0.0 exactly.
__device__ __forceinline__ bool detect_bf16(const void* tvec) {
    return ((const unsigned int*)tvec)[0] != 0u;
}

// Scalar dual-dtype load (round-3 proven).
__device__ __forceinline__ float ld(const void* p, size_t i, bool b16) {
    if (b16) return bf2f(((const unsigned short*)p)[i]);
    return ((const float*)p)[i];
}

// Param row for pixel n: [c, trend, a0..a3, b0..b3]
__device__ void compute_params(
    int n, bool b16,
    const void* __restrict__ amps,
    const void* __restrict__ phs,
    const void* __restrict__ wgts,
    const int*  __restrict__ idx,
    const void* __restrict__ coff,
    const void* __restrict__ trend,
    float outp[12])
{
    float sx[4]  = {0,0,0,0}, sxx[4] = {0,0,0,0}, swx[4] = {0,0,0,0};
    float wre[4] = {0,0,0,0}, wim[4] = {0,0,0,0};

    #pragma unroll
    for (int k = 0; k < KNB; ++k) {
        int j = idx[(size_t)n * KNB + k];
        j = (j < 0) ? 0 : ((j >= N_PTS) ? N_PTS - 1 : j);  // defensive clamp
        float wk = ld(wgts, (size_t)n * KNB + k, b16);
        #pragma unroll
        for (int i = 0; i < 4; ++i) {
            float a = ld(amps, (size_t)j * 4 + i, b16);
            float p = ld(phs,  (size_t)j * 4 + i, b16);
            sx[i]  += a;
            sxx[i] += a * a;
            swx[i] += wk * a;
            float s, c;
            __sincosf(p, &s, &c);
            wre[i] += wk * c;
            wim[i] += wk * s;
        }
    }

    outp[0] = ld(coff,  n, b16);
    outp[1] = ld(trend, n, b16);
    #pragma unroll
    for (int i = 0; i < 4; ++i) {
        float aof = ld(amps, (size_t)n * 4 + i, b16);
        float pof = ld(phs,  (size_t)n * 4 + i, b16);

        float mean  = sx[i] * (1.0f / KNB);
        float var   = fmaxf((sxx[i] - (float)KNB * mean * mean) * (1.0f / (KNB - 1)), 0.0f);
        float afa   = 0.25f / (1.0f + 0.1f * var);
        float amp_s = (1.0f - afa) * aof + afa * swx[i];

        float cons = sqrtf(wre[i] * wre[i] + wim[i] * wim[i]);
        float afp  = 0.15f * cons;
        float s, c;
        __sincosf(pof, &s, &c);
        float mre = (1.0f - afp) * c + afp * wre[i];
        float mim = (1.0f - afp) * s + afp * wim[i];
        float h   = sqrtf(mre * mre + mim * mim);
        float ai, bi;
        if (h > 1e-30f) {
            float scale = amp_s / h;
            ai = mre * scale;
            bi = mim * scale;
        } else {  // atan2(0,0)=0 -> cos=1, sin=0
            ai = amp_s;
            bi = 0.0f;
        }
        outp[2 + i] = ai;
        outp[6 + i] = bi;
    }
}

__device__ __forceinline__ void synth_row_store(
    void* out, size_t o, float v, bool b16)
{
    if (b16) ((unsigned short*)out)[o] = f2bf(v);
    else     ((float*)out)[o] = v;
}

// ---------------- Path A: two kernels via d_ws ------------------------------

__global__ __launch_bounds__(256) void smooth_kernel(
    const void* __restrict__ amps,
    const void* __restrict__ phs,
    const void* __restrict__ wgts,
    const int*  __restrict__ idx,
    const void* __restrict__ coff,
    const void* __restrict__ trend,
    const void* __restrict__ tvec,
    float*      __restrict__ params)
{
    int n = blockIdx.x * blockDim.x + threadIdx.x;
    if (n >= N_PTS) return;
    bool b16 = detect_bf16(tvec);
    float outp[12];
    compute_params(n, b16, amps, phs, wgts, idx, coff, trend, outp);
    #pragma unroll
    for (int i = 0; i < 12; ++i) params[(size_t)n * 12 + i] = outp[i];
}

__global__ __launch_bounds__(384) void synth_kernel(
    const float* __restrict__ params,
    const void*  __restrict__ tvec,
    void*        __restrict__ out)
{
    bool b16 = detect_bf16(tvec);
    int t = threadIdx.x;
    if (t >= TLEN) return;
    float tval = ld(tvec, t, b16);

    const float W0 = 25.132741228718345f;   // 2*pi*4
    const float W1 = 12.566370614359172f;   // 2*pi*2
    const float W2 = 6.283185307179586f;    // 2*pi*1
    const float W3 = 3.141592653589793f;    // 2*pi*0.5
    float s0, c0, s1, c1, s2, c2, s3, c3;
    __sincosf(W0 * tval, &s0, &c0);
    __sincosf(W1 * tval, &s1, &c1);
    __sincosf(W2 * tval, &s2, &c2);
    __sincosf(W3 * tval, &s3, &c3);

    int row0 = blockIdx.x * SYNTH_ROWS;
    int rend = min(row0 + SYNTH_ROWS, N_PTS);
    for (int n = row0; n < rend; ++n) {
        const float* p = params + (size_t)n * 12;  // uniform address -> s_load
        float v = fmaf(p[1], tval, p[0]);
        v = fmaf(p[2], s0, v);
        v = fmaf(p[3], s1, v);
        v = fmaf(p[4], s2, v);
        v = fmaf(p[5], s3, v);
        v = fmaf(p[6], c0, v);
        v = fmaf(p[7], c1, v);
        v = fmaf(p[8], c2, v);
        v = fmaf(p[9], c3, v);
        synth_row_store(out, (size_t)n * TLEN + t, v, b16);
    }
}

// ---------------- Path B: fused, zero-workspace (round-3 verbatim) ----------

__global__ __launch_bounds__(384) void fused_kernel(
    const void* __restrict__ amps,
    const void* __restrict__ phs,
    const void* __restrict__ wgts,
    const int*  __restrict__ idx,
    const void* __restrict__ coff,
    const void* __restrict__ trend,
    const void* __restrict__ tvec,
    void*       __restrict__ out)
{
    __shared__ float P[FUSED_ROWS][12];
    bool b16 = detect_bf16(tvec);

    int row0 = blockIdx.x * FUSED_ROWS;
    int tid  = threadIdx.x;

    if (tid < FUSED_ROWS) {
        int n = row0 + tid;
        if (n < N_PTS) {
            float outp[12];
            compute_params(n, b16, amps, phs, wgts, idx, coff, trend, outp);
            #pragma unroll
            for (int i = 0; i < 12; ++i) P[tid][i] = outp[i];
        }
    }
    __syncthreads();

    int t = tid;
    if (t >= TLEN) return;
    float tval = ld(tvec, t, b16);

    const float W0 = 25.132741228718345f;
    const float W1 = 12.566370614359172f;
    const float W2 = 6.283185307179586f;
    const float W3 = 3.141592653589793f;
    float s0, c0, s1, c1, s2, c2, s3, c3;
    __sincosf(W0 * tval, &s0, &c0);
    __sincosf(W1 * tval, &s1, &c1);
    __sincosf(W2 * tval, &s2, &c2);
    __sincosf(W3 * tval, &s3, &c3);

    int rend = min(row0 + FUSED_ROWS, N_PTS);
    for (int n = row0; n < rend; ++n) {
        int r = n - row0;
        float v = fmaf(P[r][1], tval, P[r][0]);
        v = fmaf(P[r][2], s0, v);
        v = fmaf(P[r][3], s1, v);
        v = fmaf(P[r][4], s2, v);
        v = fmaf(P[r][5], s3, v);
        v = fmaf(P[r][6], c0, v);
        v = fmaf(P[r][7], c1, v);
        v = fmaf(P[r][8], c2, v);
        v = fmaf(P[r][9], c3, v);
        synth_row_store(out, (size_t)n * TLEN + t, v, b16);
    }
}

extern "C" void kernel_launch(void* const* d_in, const int* in_sizes, int n_in,
                              void* d_out, int out_size, void* d_ws, size_t ws_size,
                              hipStream_t stream) {
    const void* tvec  = d_in[0];             // time_vector (365)
    const void* coff  = d_in[1];             // constant_offset (N)
    const void* trend = d_in[2];             // linear_trend (N)
    const void* amps  = d_in[3];             // seasonal_amplitudes (N,4)
    const void* phs   = d_in[4];             // seasonal_phases (N,4)
    const void* wgts  = d_in[5];             // neighbor_weights (N,12)
    const int*  idx   = (const int*)d_in[6]; // neighbor_indices (N,12) int32

    if (d_ws != nullptr && ws_size >= PARAMS_BYTES) {
        float* params = (float*)d_ws;
        smooth_kernel<<<(N_PTS + 255) / 256, 256, 0, stream>>>(
            amps, phs, wgts, idx, coff, trend, tvec, params);
        int sblk = (N_PTS + SYNTH_ROWS - 1) / SYNTH_ROWS;
        synth_kernel<<<sblk, 384, 0, stream>>>(params, tvec, d_out);
    } else {
        int fblk = (N_PTS + FUSED_ROWS - 1) / FUSED_ROWS;
        fused_kernel<<<fblk, 384, 0, stream>>>(
            amps, phs, wgts, idx, coff, trend, tvec, d_out);
    }
}